// Round 3
// baseline (191.332 us; speedup 1.0000x reference)
//
#include <hip/hip_runtime.h>
#include <math.h>

#define Bn 32
#define Rn 512
#define Dn 256
#define Pn 5532
#define MAXU 512
#define GRID 512

#define TRr 32
#define TCc 128
#define KCs 64
#define NSTG (Dn / KCs)                               // 4 stages per pc chunk
#define NBLK GRID

// ---- workspace layout (4-byte words). nll+tick+bar zeroed by host-side
// hipMemsetAsync each call; everything else read-after-write in-call
// (poison-safe: pbf rows >= U are loaded but value-gated, proven benign).
#define PBF_OFF    0
#define PBF_WORDS  (Bn*MAXU*Dn/2)
#define LBLC_OFF   (PBF_OFF + PBF_WORDS)
#define CCNT_OFF   (LBLC_OFF + Bn*Rn)
#define CURS_OFF   (CCNT_OFF + Bn*MAXU)               // START offsets
#define RLIST_OFF  (CURS_OFF + Bn*MAXU)
#define NUNIQ_OFF  (RLIST_OFF + Bn*Rn)
#define NVALID_OFF (NUNIQ_OFF + 32)
#define NLL_OFF    (NVALID_OFF + 32)
#define TICK_OFF   (NLL_OFF + 1)
#define BAR_OFF    (TICK_OFF + 1)

typedef short short8 __attribute__((ext_vector_type(8)));
typedef short short4v __attribute__((ext_vector_type(4)));
typedef float floatx4 __attribute__((ext_vector_type(4)));

__device__ __forceinline__ unsigned short bf16r(float f) {   // fp32 -> bf16 RNE
    union { float f; unsigned int u; } c; c.f = f;
    return (unsigned short)((c.u + 0x7FFFu + ((c.u >> 16) & 1u)) >> 16);
}
__device__ __forceinline__ float bfu2f(unsigned int hi16) {  // <<16'd bf16 -> f32
    union { unsigned int u; float f; } c; c.u = hi16;
    return c.f;
}

// async global->LDS, 16B per lane. LDS dest = wave-uniform base + lane*16.
__device__ __forceinline__ void async16(void* lds, const void* g) {
    auto* l3 = reinterpret_cast<__attribute__((address_space(3))) unsigned int*>(
                   reinterpret_cast<size_t>(lds));
    auto* g1 = reinterpret_cast<const __attribute__((address_space(1))) unsigned int*>(
                   reinterpret_cast<size_t>(g));
    __builtin_amdgcn_global_load_lds(g1, l3, 16, 0, 0);
}

// monotonic software grid barrier: all GRID blocks co-resident by occupancy.
// Counter zeroed by host memset each launch; never reset in-kernel.
__device__ __forceinline__ void gbar(int* bar, int target) {
    __syncthreads();                                  // block's work done
    if (threadIdx.x == 0) {
        __threadfence();                              // release (L2 writeback)
        atomicAdd(bar, 1);                            // device-scope arrive
        while (atomicAdd(bar, 0) < target)            // coherent poll
            __builtin_amdgcn_s_sleep(8);
        __threadfence();                              // acquire (invalidate)
    }
    __syncthreads();
}

// ==== single persistent kernel: A=compact, B=protos, C=GEMM+loss ====
// LDS unioned across phases: A needs 50424 B, C needs 50304 B.
__global__ __launch_bounds__(256, 2) void fused(
    const float* __restrict__ inputs, const float* __restrict__ cls,
    const int* __restrict__ roi_label, int* __restrict__ wsi,
    float* __restrict__ out)
{
    __shared__ __align__(16) char smem[50432];

    const int t = threadIdx.x;
    const int blk = blockIdx.x;
    const int lane = t & 63, wv = t >> 6;

    unsigned short* pbf = (unsigned short*)(wsi + PBF_OFF);
    int* lblc_arr = wsi + LBLC_OFF;
    int* ccnt     = wsi + CCNT_OFF;
    int* cursor   = wsi + CURS_OFF;
    int* rlist    = wsi + RLIST_OFF;
    int* nuniq    = wsi + NUNIQ_OFF;
    int* nvalid_a = wsi + NVALID_OFF;
    float* nll    = (float*)(wsi + NLL_OFF);
    int* tick     = wsi + TICK_OFF;
    int* bar      = wsi + BAR_OFF;

    // ================= phase A: per-image compact (blocks 0..31) =============
    if (blk < Bn) {
        int* cnt_l  = (int*)smem;                     // [Pn] per-label counts
        int* slot_l = cnt_l + Pn;                     // [Pn] first-touch slot
        int* scnt   = slot_l + Pn;                    // [MAXU] per-slot counts
        int* sbase  = scnt + MAXU;                    // [MAXU] start offsets
        int* scur   = sbase + MAXU;                   // [MAXU] scatter cursor
        int* ctrs   = scur + MAXU;                    // [0]=uctr, [2..5]=wave totals
        const int b = blk;
        for (int i = t; i < Pn; i += 256) cnt_l[i] = 0;
        for (int i = t; i < MAXU; i += 256) scnt[i] = 0;
        if (t == 0) ctrs[0] = 0;
        __syncthreads();
        int myl[2], mylc[2];
        #pragma unroll
        for (int j = 0; j < 2; ++j) {
            int l = roi_label[b * Rn + t + j * 256] - 1;
            myl[j] = l;
            if (l >= 0) {
                if (atomicAdd(&cnt_l[l], 1) == 0)     // first toucher claims slot
                    slot_l[l] = atomicAdd(&ctrs[0], 1);
            }
        }
        __syncthreads();
        #pragma unroll
        for (int j = 0; j < 2; ++j) {
            int lc = (myl[j] >= 0) ? slot_l[myl[j]] : -1;
            mylc[j] = lc;
            lblc_arr[b * Rn + t + j * 256] = lc;
            if (lc >= 0) atomicAdd(&scnt[lc], 1);
        }
        __syncthreads();
        const int U = ctrs[0];
        int base = 0;                                 // exclusive prefix over slots
        for (int i0 = 0; i0 < MAXU; i0 += 256) {
            int v = scnt[i0 + t], vs = v;
            #pragma unroll
            for (int off = 1; off < 64; off <<= 1) {
                int u = __shfl_up(vs, off);
                if (lane >= off) vs += u;
            }
            if (lane == 63) ctrs[2 + wv] = vs;
            __syncthreads();
            int woff = 0, tot = 0;
            #pragma unroll
            for (int w = 0; w < 4; ++w) {
                int x = ctrs[2 + w];
                if (w < wv) woff += x;
                tot += x;
            }
            int st = base + woff + (vs - v);
            sbase[i0 + t] = st;
            scur[i0 + t]  = st;
            base += tot;
            __syncthreads();
        }
        #pragma unroll
        for (int j = 0; j < 2; ++j) {                 // scatter roi ids by slot
            int lc = mylc[j];
            if (lc >= 0) {
                int pos = atomicAdd(&scur[lc], 1);
                rlist[b * Rn + pos] = t + j * 256;
            }
        }
        __syncthreads();
        for (int i = t; i < MAXU; i += 256)
            if (i < U) { ccnt[b*MAXU+i] = scnt[i]; cursor[b*MAXU+i] = sbase[i]; }
        if (t == 0) { nuniq[b] = U; nvalid_a[b] = base; }
    }

    gbar(bar, GRID);                                  // A results visible

    // ================= phase B: protos (all 512 blocks, 32 slots each) =======
    {
        const int gs0 = blk * 32 + wv * 8;            // 8 slots per wave, same image
        const int b = gs0 >> 9;
        const int Ub = nuniq[b];
        for (int i = 0; i < 8; ++i) {
            int c = (gs0 + i) & (MAXU - 1);
            if (c >= Ub) continue;
            int s = b * MAXU + c;
            int cnt = ccnt[s], start = cursor[s];
            float a0 = 0.f, a1 = 0.f, a2 = 0.f, a3 = 0.f;
            for (int k = 0; k < cnt; ++k) {
                int row = b * Rn + rlist[b * Rn + start + k];
                float cw = cls[row];
                float4 v = *(const float4*)&inputs[(size_t)row * Dn + lane * 4];
                // bf16-round-trip: bit-identical to the old xbf path
                a0 += bfu2f(((unsigned)bf16r(v.x * cw)) << 16);
                a1 += bfu2f(((unsigned)bf16r(v.y * cw)) << 16);
                a2 += bfu2f(((unsigned)bf16r(v.z * cw)) << 16);
                a3 += bfu2f(((unsigned)bf16r(v.w * cw)) << 16);
            }
            float inv = 1.0f / (float)cnt;
            a0 *= inv; a1 *= inv; a2 *= inv; a3 *= inv;
            float ss = a0*a0 + a1*a1 + a2*a2 + a3*a3;
            #pragma unroll
            for (int off = 32; off > 0; off >>= 1) ss += __shfl_xor(ss, off);
            float sc = 1.0f / fmaxf(sqrtf(ss), 1e-12f);
            short4v o;
            o[0] = (short)bf16r(a0 * sc); o[1] = (short)bf16r(a1 * sc);
            o[2] = (short)bf16r(a2 * sc); o[3] = (short)bf16r(a3 * sc);
            *(short4v*)&pbf[(size_t)s * Dn + lane * 4] = o;
        }
    }

    gbar(bar, 2 * GRID);                              // pbf visible

    // ================= phase C: 32 rois x ALL proto cols per block ===========
    {
        unsigned short* xs  = (unsigned short*)smem;            // [32*256] bf16
        unsigned short* psb = xs + TRr * Dn;                    // 2 x [128*64] dbuf
        int*   lblc = (int*)(psb + 2 * TCc * KCs);              // [32]
        float* es_l = (float*)(lblc + TRr);                     // [4*32]
        float* ds_l = es_l + 4 * TRr;                           // [4*32]

        const int w = wv;
        const int q = lane >> 4, r15 = lane & 15;
        const int rt = blk & 15;
        const int b  = blk >> 4;
        const int roiBase = rt * TRr;
        const int U = nuniq[b];
        const int nch = (U <= 0) ? 1 : ((U + TCc - 1) >> 7);

        if (t < TRr) lblc[t] = lblc_arr[b * Rn + roiBase + t];

#define ISSUE_PS(PC, ST, BUF)                                                \
    do {                                                                     \
        _Pragma("unroll")                                                    \
        for (int i_ = 0; i_ < 4; ++i_) {                                     \
            int ci_ = i_ * 256 + w * 64 + lane;                              \
            int pr_ = ci_ >> 3, gp_ = ci_ & 7;                               \
            int g_ = gp_ ^ (pr_ & 7);                                        \
            async16(psb + (size_t)(BUF) * (TCc * KCs)                        \
                        + (size_t)(i_ * 256 + w * 64) * 8,                   \
                    pbf + (size_t)(b * MAXU + (PC) * TCc + pr_) * Dn         \
                        + (ST) * KCs + g_ * 8);                              \
        }                                                                    \
    } while (0)

        ISSUE_PS(0, 0, 0);                            // overlaps with A-convert

        // A-tile: f32 -> bf16 (bit-identical) -> swizzled LDS (gpos = g ^ (row&7))
        {
            const int row = t >> 3, seg = t & 7;      // 8 threads per roi row
            const size_t gbase = (size_t)(b * Rn + roiBase + row) * Dn + seg * 32;
            const float cw = cls[b * Rn + roiBase + row];
            #pragma unroll
            for (int jj = 0; jj < 4; ++jj) {
                float4 v0 = *(const float4*)&inputs[gbase + jj * 8];
                float4 v1 = *(const float4*)&inputs[gbase + jj * 8 + 4];
                short8 o;
                o[0] = (short)bf16r(v0.x * cw); o[1] = (short)bf16r(v0.y * cw);
                o[2] = (short)bf16r(v0.z * cw); o[3] = (short)bf16r(v0.w * cw);
                o[4] = (short)bf16r(v1.x * cw); o[5] = (short)bf16r(v1.y * cw);
                o[6] = (short)bf16r(v1.z * cw); o[7] = (short)bf16r(v1.w * cw);
                int gpos = (seg * 4 + jj) ^ (row & 7);
                *(short8*)&xs[row * Dn + gpos * 8] = o;
            }
        }
        __syncthreads();                              // xs + ps[0] resident

        // preload all A fragments into registers: 64 VGPRs
        short8 areg[2][8];
        #pragma unroll
        for (int mt = 0; mt < 2; ++mt)
            #pragma unroll
            for (int kcs = 0; kcs < 8; ++kcs) {
                int row = mt * 16 + r15;
                int gpos = (kcs * 4 + q) ^ (row & 7);
                areg[mt][kcs] = *(const short8*)&xs[row * Dn + gpos * 8];
            }

        int lcr[2][4];
        float esum[2][4], dsum[2][4];
        #pragma unroll
        for (int mt = 0; mt < 2; ++mt)
            #pragma unroll
            for (int reg = 0; reg < 4; ++reg) {
                lcr[mt][reg] = lblc[mt * 16 + q * 4 + reg];
                esum[mt][reg] = 0.f; dsum[mt][reg] = 0.f;
            }

        for (int pc = 0; pc < nch; ++pc) {
            floatx4 acc[2][2];
            #pragma unroll
            for (int mt = 0; mt < 2; ++mt) {
                acc[mt][0] = (floatx4)0.f; acc[mt][1] = (floatx4)0.f;
            }

            #pragma unroll
            for (int st = 0; st < NSTG; ++st) {
                const int cur = st & 1;               // NSTG even -> static parity
                __syncthreads();                      // ps[cur] resident
                int ns = pc * NSTG + st + 1;
                if (ns < nch * NSTG) ISSUE_PS(ns >> 2, ns & 3, cur ^ 1);
                const unsigned short* pscur = psb + (size_t)cur * (TCc * KCs);
                #pragma unroll
                for (int kk = 0; kk < 2; ++kk) {
                    short8 bb[2];
                    #pragma unroll
                    for (int nt = 0; nt < 2; ++nt) {
                        int r = w * 32 + nt * 16 + r15;
                        int gpos = (kk * 4 + q) ^ (r & 7);
                        bb[nt] = *(const short8*)&pscur[r * KCs + gpos * 8];
                    }
                    #pragma unroll
                    for (int mt = 0; mt < 2; ++mt) {
                        acc[mt][0] = __builtin_amdgcn_mfma_f32_16x16x32_bf16(
                            areg[mt][st * 2 + kk], bb[0], acc[mt][0], 0, 0, 0);
                        acc[mt][1] = __builtin_amdgcn_mfma_f32_16x16x32_bf16(
                            areg[mt][st * 2 + kk], bb[1], acc[mt][1], 0, 0, 0);
                    }
                }
            }

            // per-pc epilogue in registers; C/D: n = r15, m = q*4 + reg
            #pragma unroll
            for (int nt = 0; nt < 2; ++nt) {
                int c = pc * TCc + w * 32 + nt * 16 + r15;
                bool v = c < U;
                #pragma unroll
                for (int mt = 0; mt < 2; ++mt)
                    #pragma unroll
                    for (int reg = 0; reg < 4; ++reg) {
                        float d = acc[mt][nt][reg];
                        if (v) esum[mt][reg] += __expf(d);
                        if (c == lcr[mt][reg]) dsum[mt][reg] += d;
                    }
            }
        }
#undef ISSUE_PS

        // cross-lane (16) then cross-wave (LDS) combine; one atomic per block
        #pragma unroll
        for (int mt = 0; mt < 2; ++mt)
            #pragma unroll
            for (int reg = 0; reg < 4; ++reg) {
                float e = esum[mt][reg], d = dsum[mt][reg];
                #pragma unroll
                for (int off = 1; off < 16; off <<= 1) {
                    e += __shfl_xor(e, off);
                    d += __shfl_xor(d, off);
                }
                if (r15 == 0) {
                    int row = mt * 16 + q * 4 + reg;
                    es_l[w * TRr + row] = e;
                    ds_l[w * TRr + row] = d;
                }
            }
        __syncthreads();
        if (t < TRr) {
            float es = es_l[t] + es_l[TRr + t] + es_l[2*TRr + t] + es_l[3*TRr + t];
            float ds = ds_l[t] + ds_l[TRr + t] + ds_l[2*TRr + t] + ds_l[3*TRr + t];
            float val = (lblc[t] >= 0) ? (__logf(es) - ds) : 0.f;
            #pragma unroll
            for (int off = 1; off < 32; off <<= 1) val += __shfl_xor(val, off);
            if (t == 0) {
                atomicAdd(nll, val);
                __threadfence();                      // order nll add vs ticket
                int old = atomicAdd(tick, 1);
                if (old == NBLK - 1) {                // last block finalizes
                    float total = atomicAdd(nll, 0.0f);   // coherent read
                    int nv = 0;
                    #pragma unroll
                    for (int i = 0; i < Bn / 4; ++i) {
                        int4 vv = ((const int4*)nvalid_a)[i];
                        nv += vv.x + vv.y + vv.z + vv.w;
                    }
                    out[0] = total / fmaxf((float)nv, 1.0f);
                }
            }
        }
    }
}

extern "C" void kernel_launch(void* const* d_in, const int* in_sizes, int n_in,
                              void* d_out, int out_size, void* d_ws, size_t ws_size,
                              hipStream_t stream) {
    const float* inputs = (const float*)d_in[0];
    const float* cls    = (const float*)d_in[1];
    const int*   roi    = (const int*)d_in[2];
    int* wsi   = (int*)d_ws;
    float* out = (float*)d_out;

    // zero nll + tick + barrier (12 B) — capture-safe async memset
    hipMemsetAsync((char*)d_ws + (size_t)NLL_OFF * 4, 0, 12, stream);
    fused<<<GRID, 256, 0, stream>>>(inputs, cls, roi, wsi, out);
}

// Round 4
// 185.084 us; speedup vs baseline: 1.0338x; 1.0338x over previous
//
#include <hip/hip_runtime.h>
#include <math.h>

#define Bn 32
#define Rn 512
#define Dn 256
#define Pn 5532
#define MAXU 512
#define GRID 512

#define TRr 32
#define TCc 128
#define KCs 64
#define NSTG (Dn / KCs)                               // 4 stages per pc chunk
#define NBLK GRID

// ---- workspace layout (4-byte words). nll+tick+bar zeroed by host-side
// hipMemsetAsync each call; everything else read-after-write in-call
// (poison-safe: pbf rows >= U are loaded but value-gated, proven benign).
#define PBF_OFF    0
#define PBF_WORDS  (Bn*MAXU*Dn/2)
#define LBLC_OFF   (PBF_OFF + PBF_WORDS)
#define CCNT_OFF   (LBLC_OFF + Bn*Rn)
#define CURS_OFF   (CCNT_OFF + Bn*MAXU)               // START offsets
#define RLIST_OFF  (CURS_OFF + Bn*MAXU)
#define NUNIQ_OFF  (RLIST_OFF + Bn*Rn)
#define NVALID_OFF (NUNIQ_OFF + 32)
#define NLL_OFF    (NVALID_OFF + 32)
#define TICK_OFF   (NLL_OFF + 1)
#define BAR_OFF    (TICK_OFF + 1)

typedef short short8 __attribute__((ext_vector_type(8)));
typedef short short4v __attribute__((ext_vector_type(4)));
typedef float floatx4 __attribute__((ext_vector_type(4)));

__device__ __forceinline__ unsigned short bf16r(float f) {   // fp32 -> bf16 RNE
    union { float f; unsigned int u; } c; c.f = f;
    return (unsigned short)((c.u + 0x7FFFu + ((c.u >> 16) & 1u)) >> 16);
}
__device__ __forceinline__ float bfu2f(unsigned int hi16) {  // <<16'd bf16 -> f32
    union { unsigned int u; float f; } c; c.u = hi16;
    return c.f;
}

// async global->LDS, 16B per lane. LDS dest = wave-uniform base + lane*16.
__device__ __forceinline__ void async16(void* lds, const void* g) {
    auto* l3 = reinterpret_cast<__attribute__((address_space(3))) unsigned int*>(
                   reinterpret_cast<size_t>(lds));
    auto* g1 = reinterpret_cast<const __attribute__((address_space(1))) unsigned int*>(
                   reinterpret_cast<size_t>(g));
    __builtin_amdgcn_global_load_lds(g1, l3, 16, 0, 0);
}

// monotonic software grid barrier. Arrive = one atomic RMW per block; poll =
// coherent LOAD (no RMW line-ownership storm — R3's atomicAdd(bar,0) poll
// serialized 512 pollers across 8 non-coherent L2s and cost ~100 us).
__device__ __forceinline__ void gbar(int* bar, int target) {
    __syncthreads();                                  // block's work done
    if (threadIdx.x == 0) {
        __threadfence();                              // release (L2 writeback)
        atomicAdd(bar, 1);                            // device-scope arrive
        while (__hip_atomic_load(bar, __ATOMIC_RELAXED,
                                 __HIP_MEMORY_SCOPE_AGENT) < target)
            __builtin_amdgcn_s_sleep(2);              // coherent load poll
        __threadfence();                              // acquire (invalidate)
    }
    __syncthreads();
}

// ==== single persistent kernel: A=compact, B=protos, C=GEMM+loss ====
// LDS unioned across phases: A needs 50424 B, C needs 50304 B.
__global__ __launch_bounds__(256, 2) void fused(
    const float* __restrict__ inputs, const float* __restrict__ cls,
    const int* __restrict__ roi_label, int* __restrict__ wsi,
    float* __restrict__ out)
{
    __shared__ __align__(16) char smem[50432];

    const int t = threadIdx.x;
    const int blk = blockIdx.x;
    const int lane = t & 63, wv = t >> 6;

    unsigned short* pbf = (unsigned short*)(wsi + PBF_OFF);
    int* lblc_arr = wsi + LBLC_OFF;
    int* ccnt     = wsi + CCNT_OFF;
    int* cursor   = wsi + CURS_OFF;
    int* rlist    = wsi + RLIST_OFF;
    int* nuniq    = wsi + NUNIQ_OFF;
    int* nvalid_a = wsi + NVALID_OFF;
    float* nll    = (float*)(wsi + NLL_OFF);
    int* tick     = wsi + TICK_OFF;
    int* bar      = wsi + BAR_OFF;

    // ================= phase A: per-image compact (blocks 0..31) =============
    if (blk < Bn) {
        int* cnt_l  = (int*)smem;                     // [Pn] per-label counts
        int* slot_l = cnt_l + Pn;                     // [Pn] first-touch slot
        int* scnt   = slot_l + Pn;                    // [MAXU] per-slot counts
        int* sbase  = scnt + MAXU;                    // [MAXU] start offsets
        int* scur   = sbase + MAXU;                   // [MAXU] scatter cursor
        int* ctrs   = scur + MAXU;                    // [0]=uctr, [2..5]=wave totals
        const int b = blk;
        for (int i = t; i < Pn; i += 256) cnt_l[i] = 0;
        for (int i = t; i < MAXU; i += 256) scnt[i] = 0;
        if (t == 0) ctrs[0] = 0;
        __syncthreads();
        int myl[2], mylc[2];
        #pragma unroll
        for (int j = 0; j < 2; ++j) {
            int l = roi_label[b * Rn + t + j * 256] - 1;
            myl[j] = l;
            if (l >= 0) {
                if (atomicAdd(&cnt_l[l], 1) == 0)     // first toucher claims slot
                    slot_l[l] = atomicAdd(&ctrs[0], 1);
            }
        }
        __syncthreads();
        #pragma unroll
        for (int j = 0; j < 2; ++j) {
            int lc = (myl[j] >= 0) ? slot_l[myl[j]] : -1;
            mylc[j] = lc;
            lblc_arr[b * Rn + t + j * 256] = lc;
            if (lc >= 0) atomicAdd(&scnt[lc], 1);
        }
        __syncthreads();
        const int U = ctrs[0];
        int base = 0;                                 // exclusive prefix over slots
        for (int i0 = 0; i0 < MAXU; i0 += 256) {
            int v = scnt[i0 + t], vs = v;
            #pragma unroll
            for (int off = 1; off < 64; off <<= 1) {
                int u = __shfl_up(vs, off);
                if (lane >= off) vs += u;
            }
            if (lane == 63) ctrs[2 + wv] = vs;
            __syncthreads();
            int woff = 0, tot = 0;
            #pragma unroll
            for (int w = 0; w < 4; ++w) {
                int x = ctrs[2 + w];
                if (w < wv) woff += x;
                tot += x;
            }
            int st = base + woff + (vs - v);
            sbase[i0 + t] = st;
            scur[i0 + t]  = st;
            base += tot;
            __syncthreads();
        }
        #pragma unroll
        for (int j = 0; j < 2; ++j) {                 // scatter roi ids by slot
            int lc = mylc[j];
            if (lc >= 0) {
                int pos = atomicAdd(&scur[lc], 1);
                rlist[b * Rn + pos] = t + j * 256;
            }
        }
        __syncthreads();
        for (int i = t; i < MAXU; i += 256)
            if (i < U) { ccnt[b*MAXU+i] = scnt[i]; cursor[b*MAXU+i] = sbase[i]; }
        if (t == 0) { nuniq[b] = U; nvalid_a[b] = base; }
    }

    gbar(bar, GRID);                                  // A results visible

    // ===== phase B: protos (512 blocks x 4 waves x 8 slots), batched ILP =====
    {
        const int gs0 = blk * 32 + wv * 8;            // 8 slots per wave, same image
        const int b = gs0 >> 9;
        const int Ub = nuniq[b];
        int cs[8], stt[8];
        #pragma unroll
        for (int i = 0; i < 8; ++i) {                 // 16 independent meta loads
            int c = (gs0 + i) & (MAXU - 1);
            bool ok = (c < Ub);
            int s = b * MAXU + c;
            cs[i]  = ok ? ccnt[s]   : 0;
            stt[i] = ok ? cursor[s] : 0;
        }
        int r0[8];
        #pragma unroll
        for (int i = 0; i < 8; ++i)                   // 8 independent rlist loads
            r0[i] = cs[i] ? rlist[b * Rn + stt[i]] : 0;
        float4 v4[8]; float cwv[8];
        #pragma unroll
        for (int i = 0; i < 8; ++i) {                 // 16 independent row loads
            int row = b * Rn + r0[i];                 // row 0 when invalid (benign)
            cwv[i] = cls[row];
            v4[i]  = *(const float4*)&inputs[(size_t)row * Dn + lane * 4];
        }
        float4 acc[8];
        #pragma unroll
        for (int i = 0; i < 8; ++i) {                 // bf16 round-trip, bit-identical
            acc[i].x = bfu2f(((unsigned)bf16r(v4[i].x * cwv[i])) << 16);
            acc[i].y = bfu2f(((unsigned)bf16r(v4[i].y * cwv[i])) << 16);
            acc[i].z = bfu2f(((unsigned)bf16r(v4[i].z * cwv[i])) << 16);
            acc[i].w = bfu2f(((unsigned)bf16r(v4[i].w * cwv[i])) << 16);
        }
        #pragma unroll
        for (int i = 0; i < 8; ++i) {                 // rare cnt>1 tail, same order
            for (int k = 1; k < cs[i]; ++k) {
                int row = b * Rn + rlist[b * Rn + stt[i] + k];
                float cw = cls[row];
                float4 v = *(const float4*)&inputs[(size_t)row * Dn + lane * 4];
                acc[i].x += bfu2f(((unsigned)bf16r(v.x * cw)) << 16);
                acc[i].y += bfu2f(((unsigned)bf16r(v.y * cw)) << 16);
                acc[i].z += bfu2f(((unsigned)bf16r(v.z * cw)) << 16);
                acc[i].w += bfu2f(((unsigned)bf16r(v.w * cw)) << 16);
            }
        }
        #pragma unroll
        for (int i = 0; i < 8; ++i) {
            if (!cs[i]) continue;
            float inv = 1.0f / (float)cs[i];
            float a0 = acc[i].x * inv, a1 = acc[i].y * inv;
            float a2 = acc[i].z * inv, a3 = acc[i].w * inv;
            float ss = a0*a0 + a1*a1 + a2*a2 + a3*a3;
            #pragma unroll
            for (int off = 32; off > 0; off >>= 1) ss += __shfl_xor(ss, off);
            float sc = 1.0f / fmaxf(sqrtf(ss), 1e-12f);
            short4v o;
            o[0] = (short)bf16r(a0 * sc); o[1] = (short)bf16r(a1 * sc);
            o[2] = (short)bf16r(a2 * sc); o[3] = (short)bf16r(a3 * sc);
            int s = b * MAXU + ((gs0 + i) & (MAXU - 1));
            *(short4v*)&pbf[(size_t)s * Dn + lane * 4] = o;
        }
    }

    gbar(bar, 2 * GRID);                              // pbf visible

    // ================= phase C: 32 rois x ALL proto cols per block ===========
    {
        unsigned short* xs  = (unsigned short*)smem;            // [32*256] bf16
        unsigned short* psb = xs + TRr * Dn;                    // 2 x [128*64] dbuf
        int*   lblc = (int*)(psb + 2 * TCc * KCs);              // [32]
        float* es_l = (float*)(lblc + TRr);                     // [4*32]
        float* ds_l = es_l + 4 * TRr;                           // [4*32]

        const int w = wv;
        const int q = lane >> 4, r15 = lane & 15;
        const int rt = blk & 15;
        const int b  = blk >> 4;
        const int roiBase = rt * TRr;
        const int U = nuniq[b];
        const int nch = (U <= 0) ? 1 : ((U + TCc - 1) >> 7);

        if (t < TRr) lblc[t] = lblc_arr[b * Rn + roiBase + t];

#define ISSUE_PS(PC, ST, BUF)                                                \
    do {                                                                     \
        _Pragma("unroll")                                                    \
        for (int i_ = 0; i_ < 4; ++i_) {                                     \
            int ci_ = i_ * 256 + w * 64 + lane;                              \
            int pr_ = ci_ >> 3, gp_ = ci_ & 7;                               \
            int g_ = gp_ ^ (pr_ & 7);                                        \
            async16(psb + (size_t)(BUF) * (TCc * KCs)                        \
                        + (size_t)(i_ * 256 + w * 64) * 8,                   \
                    pbf + (size_t)(b * MAXU + (PC) * TCc + pr_) * Dn         \
                        + (ST) * KCs + g_ * 8);                              \
        }                                                                    \
    } while (0)

        ISSUE_PS(0, 0, 0);                            // overlaps with A-convert

        // A-tile: f32 -> bf16 (bit-identical) -> swizzled LDS (gpos = g ^ (row&7))
        {
            const int row = t >> 3, seg = t & 7;      // 8 threads per roi row
            const size_t gbase = (size_t)(b * Rn + roiBase + row) * Dn + seg * 32;
            const float cw = cls[b * Rn + roiBase + row];
            #pragma unroll
            for (int jj = 0; jj < 4; ++jj) {
                float4 v0 = *(const float4*)&inputs[gbase + jj * 8];
                float4 v1 = *(const float4*)&inputs[gbase + jj * 8 + 4];
                short8 o;
                o[0] = (short)bf16r(v0.x * cw); o[1] = (short)bf16r(v0.y * cw);
                o[2] = (short)bf16r(v0.z * cw); o[3] = (short)bf16r(v0.w * cw);
                o[4] = (short)bf16r(v1.x * cw); o[5] = (short)bf16r(v1.y * cw);
                o[6] = (short)bf16r(v1.z * cw); o[7] = (short)bf16r(v1.w * cw);
                int gpos = (seg * 4 + jj) ^ (row & 7);
                *(short8*)&xs[row * Dn + gpos * 8] = o;
            }
        }
        __syncthreads();                              // xs + ps[0] resident

        // preload all A fragments into registers: 64 VGPRs
        short8 areg[2][8];
        #pragma unroll
        for (int mt = 0; mt < 2; ++mt)
            #pragma unroll
            for (int kcs = 0; kcs < 8; ++kcs) {
                int row = mt * 16 + r15;
                int gpos = (kcs * 4 + q) ^ (row & 7);
                areg[mt][kcs] = *(const short8*)&xs[row * Dn + gpos * 8];
            }

        int lcr[2][4];
        float esum[2][4], dsum[2][4];
        #pragma unroll
        for (int mt = 0; mt < 2; ++mt)
            #pragma unroll
            for (int reg = 0; reg < 4; ++reg) {
                lcr[mt][reg] = lblc[mt * 16 + q * 4 + reg];
                esum[mt][reg] = 0.f; dsum[mt][reg] = 0.f;
            }

        for (int pc = 0; pc < nch; ++pc) {
            floatx4 acc[2][2];
            #pragma unroll
            for (int mt = 0; mt < 2; ++mt) {
                acc[mt][0] = (floatx4)0.f; acc[mt][1] = (floatx4)0.f;
            }

            #pragma unroll
            for (int st = 0; st < NSTG; ++st) {
                const int cur = st & 1;               // NSTG even -> static parity
                __syncthreads();                      // ps[cur] resident
                int ns = pc * NSTG + st + 1;
                if (ns < nch * NSTG) ISSUE_PS(ns >> 2, ns & 3, cur ^ 1);
                const unsigned short* pscur = psb + (size_t)cur * (TCc * KCs);
                #pragma unroll
                for (int kk = 0; kk < 2; ++kk) {
                    short8 bb[2];
                    #pragma unroll
                    for (int nt = 0; nt < 2; ++nt) {
                        int r = w * 32 + nt * 16 + r15;
                        int gpos = (kk * 4 + q) ^ (r & 7);
                        bb[nt] = *(const short8*)&pscur[r * KCs + gpos * 8];
                    }
                    #pragma unroll
                    for (int mt = 0; mt < 2; ++mt) {
                        acc[mt][0] = __builtin_amdgcn_mfma_f32_16x16x32_bf16(
                            areg[mt][st * 2 + kk], bb[0], acc[mt][0], 0, 0, 0);
                        acc[mt][1] = __builtin_amdgcn_mfma_f32_16x16x32_bf16(
                            areg[mt][st * 2 + kk], bb[1], acc[mt][1], 0, 0, 0);
                    }
                }
            }

            // per-pc epilogue in registers; C/D: n = r15, m = q*4 + reg
            #pragma unroll
            for (int nt = 0; nt < 2; ++nt) {
                int c = pc * TCc + w * 32 + nt * 16 + r15;
                bool v = c < U;
                #pragma unroll
                for (int mt = 0; mt < 2; ++mt)
                    #pragma unroll
                    for (int reg = 0; reg < 4; ++reg) {
                        float d = acc[mt][nt][reg];
                        if (v) esum[mt][reg] += __expf(d);
                        if (c == lcr[mt][reg]) dsum[mt][reg] += d;
                    }
            }
        }
#undef ISSUE_PS

        // cross-lane (16) then cross-wave (LDS) combine; one atomic per block
        #pragma unroll
        for (int mt = 0; mt < 2; ++mt)
            #pragma unroll
            for (int reg = 0; reg < 4; ++reg) {
                float e = esum[mt][reg], d = dsum[mt][reg];
                #pragma unroll
                for (int off = 1; off < 16; off <<= 1) {
                    e += __shfl_xor(e, off);
                    d += __shfl_xor(d, off);
                }
                if (r15 == 0) {
                    int row = mt * 16 + q * 4 + reg;
                    es_l[w * TRr + row] = e;
                    ds_l[w * TRr + row] = d;
                }
            }
        __syncthreads();
        if (t < TRr) {
            float es = es_l[t] + es_l[TRr + t] + es_l[2*TRr + t] + es_l[3*TRr + t];
            float ds = ds_l[t] + ds_l[TRr + t] + ds_l[2*TRr + t] + ds_l[3*TRr + t];
            float val = (lblc[t] >= 0) ? (__logf(es) - ds) : 0.f;
            #pragma unroll
            for (int off = 1; off < 32; off <<= 1) val += __shfl_xor(val, off);
            if (t == 0) {
                atomicAdd(nll, val);
                __threadfence();                      // order nll add vs ticket
                int old = atomicAdd(tick, 1);
                if (old == NBLK - 1) {                // last block finalizes
                    float total = atomicAdd(nll, 0.0f);   // coherent read
                    int nv = 0;
                    #pragma unroll
                    for (int i = 0; i < Bn / 4; ++i) {
                        int4 vv = ((const int4*)nvalid_a)[i];
                        nv += vv.x + vv.y + vv.z + vv.w;
                    }
                    out[0] = total / fmaxf((float)nv, 1.0f);
                }
            }
        }
    }
}

extern "C" void kernel_launch(void* const* d_in, const int* in_sizes, int n_in,
                              void* d_out, int out_size, void* d_ws, size_t ws_size,
                              hipStream_t stream) {
    const float* inputs = (const float*)d_in[0];
    const float* cls    = (const float*)d_in[1];
    const int*   roi    = (const int*)d_in[2];
    int* wsi   = (int*)d_ws;
    float* out = (float*)d_out;

    // zero nll + tick + barrier (12 B) — capture-safe async memset
    hipMemsetAsync((char*)d_ws + (size_t)NLL_OFF * 4, 0, 12, stream);
    fused<<<GRID, 256, 0, stream>>>(inputs, cls, roi, wsi, out);
}

// Round 5
// 126.816 us; speedup vs baseline: 1.5087x; 1.4595x over previous
//
#include <hip/hip_runtime.h>
#include <math.h>

#define Bn 32
#define Rn 512
#define Dn 256
#define Pn 5532
#define MAXU 512

#define TRr 32
#define TCc 128
#define KCs 64
#define NSTG (Dn / KCs)                               // 4 stages per pc chunk
#define NBLK ((Rn / TRr) * Bn)                        // 512 blocks in k3

// ---- workspace layout (4-byte words). nll+tick zeroed by k12 block 0 each
// call; everything else read-after-write in-call (poison-safe: pbf rows >= U
// are loaded but value-gated, proven benign R0-R4).
#define PBF_OFF    0
#define PBF_WORDS  (Bn*MAXU*Dn/2)
#define LBLC_OFF   (PBF_OFF + PBF_WORDS)
#define NUNIQ_OFF  (LBLC_OFF + Bn*Rn)
#define NVALID_OFF (NUNIQ_OFF + 32)
#define NLL_OFF    (NVALID_OFF + 32)
#define TICK_OFF   (NLL_OFF + 1)

typedef short short8 __attribute__((ext_vector_type(8)));
typedef short short4v __attribute__((ext_vector_type(4)));
typedef float floatx4 __attribute__((ext_vector_type(4)));

__device__ __forceinline__ unsigned short bf16r(float f) {   // fp32 -> bf16 RNE
    union { float f; unsigned int u; } c; c.f = f;
    return (unsigned short)((c.u + 0x7FFFu + ((c.u >> 16) & 1u)) >> 16);
}
__device__ __forceinline__ float bfu2f(unsigned int hi16) {  // <<16'd bf16 -> f32
    union { unsigned int u; float f; } c; c.u = hi16;
    return c.f;
}

// async global->LDS, 16B per lane. LDS dest = wave-uniform base + lane*16.
__device__ __forceinline__ void async16(void* lds, const void* g) {
    auto* l3 = reinterpret_cast<__attribute__((address_space(3))) unsigned int*>(
                   reinterpret_cast<size_t>(lds));
    auto* g1 = reinterpret_cast<const __attribute__((address_space(1))) unsigned int*>(
                   reinterpret_cast<size_t>(g));
    __builtin_amdgcn_global_load_lds(g1, l3, 16, 0, 0);
}

// ==== k12: ONE block per image: compact (R0-proven) + protos, all metadata
// in LDS (no global cursor/rlist round-trips, no grid barrier — the k1->k2
// dependency is intra-block; R3/R4 showed device-wide soft barriers cost
// ~40-45 us each, so they are banned).
__global__ __launch_bounds__(1024) void k12_prep_proto(
    const float* __restrict__ inputs, const float* __restrict__ cls,
    const int* __restrict__ roi_label,
    unsigned short* __restrict__ pbf, int* __restrict__ lblc_arr,
    int* __restrict__ nuniq, int* __restrict__ nvalid_arr,
    int* __restrict__ zwords)
{
    __shared__ int cnt_lds[Pn];                       // 22.1 KB
    __shared__ int cmap_lds[Pn];                      // 22.1 KB
    __shared__ int curs_lds[MAXU];                    // start -> end cursors
    __shared__ int scnt_lds[MAXU];                    // per-slot counts
    __shared__ int rl_lds[Rn];                        // roi ids grouped by slot
    __shared__ int wpres[16], wcnt[16];

    const int b = blockIdx.x;
    const int t = threadIdx.x;
    const int lane = t & 63, wid = t >> 6;            // 16 waves

    if (b == 0 && t == 0) { zwords[0] = 0; zwords[1] = 0; }   // nll, tick

    // ---- compact: counts from this image's 512 labels, all in LDS ----
    for (int i = t; i < Pn; i += 1024) cnt_lds[i] = 0;
    __syncthreads();
    int mylbl = -1;
    if (t < Rn) {
        mylbl = roi_label[b * Rn + t] - 1;
        if (mylbl >= 0) atomicAdd(&cnt_lds[mylbl], 1);
    }
    __syncthreads();

    int basePres = 0, baseCnt = 0;                    // replicated in all threads
    for (int i0 = 0; i0 < Pn; i0 += 1024) {           // 6 chunks
        int i = i0 + t;
        int cnt = (i < Pn) ? cnt_lds[i] : 0;
        bool pres = cnt > 0;
        unsigned long long mask = __ballot(pres);
        int pfx_pres = __popcll(mask & ((1ULL << lane) - 1ULL));
        int v = cnt;
        #pragma unroll
        for (int off = 1; off < 64; off <<= 1) {
            int u = __shfl_up(v, off);
            if (lane >= off) v += u;
        }
        int pfx_cnt = v - cnt;                        // exclusive
        if (lane == 63) { wpres[wid] = __popcll(mask); wcnt[wid] = v; }
        __syncthreads();
        int woffP = 0, totP = 0, woffC = 0, totC = 0;
        #pragma unroll
        for (int w = 0; w < 16; ++w) {
            int p = wpres[w], c = wcnt[w];
            if (w < wid) { woffP += p; woffC += c; }
            totP += p; totC += c;
        }
        if (pres) {
            int c = basePres + woffP + pfx_pres;      // compact slot < MAXU
            cmap_lds[i] = c;
            scnt_lds[c] = cnt;
            curs_lds[c] = baseCnt + woffC + pfx_cnt;  // start offset
        }
        basePres += totP; baseCnt += totC;
        __syncthreads();
    }
    // per-roi compact label + scatter roi ids into LDS rlist
    if (t < Rn) {
        int lc = (mylbl >= 0) ? cmap_lds[mylbl] : -1;
        lblc_arr[b * Rn + t] = lc;
        if (lc >= 0) {
            int pos = atomicAdd(&curs_lds[lc], 1);    // curs becomes END offset
            rl_lds[pos] = t;
        }
    }
    if (t == 0) { nuniq[b] = basePres; nvalid_arr[b] = baseCnt; }
    __syncthreads();
    const int U = basePres;

    // ---- protos: wave wid owns slots wid+16k, batched 4-deep for ILP ----
    for (int cb = wid; cb < U; cb += 64) {
        int cntj[4], stj[4];
        #pragma unroll
        for (int j = 0; j < 4; ++j) {                 // metadata from LDS (cheap)
            int c = cb + 16 * j;
            bool ok = c < U;
            int cnt = ok ? scnt_lds[c] : 0;
            cntj[j] = cnt;
            stj[j]  = ok ? (curs_lds[c] - cnt) : 0;   // end - cnt = start
        }
        int rj[4];
        #pragma unroll
        for (int j = 0; j < 4; ++j) rj[j] = cntj[j] ? rl_lds[stj[j]] : 0;
        float cwj[4]; float4 vj[4];
        #pragma unroll
        for (int j = 0; j < 4; ++j) {                 // 8 independent global loads
            int row = b * Rn + rj[j];                 // row 0 when invalid (benign)
            cwj[j] = cls[row];
            vj[j]  = *(const float4*)&inputs[(size_t)row * Dn + lane * 4];
        }
        #pragma unroll
        for (int j = 0; j < 4; ++j) {
            if (!cntj[j]) continue;
            // bf16 round-trip: bit-identical to the proven xbf path
            float a0 = bfu2f(((unsigned)bf16r(vj[j].x * cwj[j])) << 16);
            float a1 = bfu2f(((unsigned)bf16r(vj[j].y * cwj[j])) << 16);
            float a2 = bfu2f(((unsigned)bf16r(vj[j].z * cwj[j])) << 16);
            float a3 = bfu2f(((unsigned)bf16r(vj[j].w * cwj[j])) << 16);
            for (int k = 1; k < cntj[j]; ++k) {       // rare cnt>1 tail, same order
                int row = b * Rn + rl_lds[stj[j] + k];
                float cw = cls[row];
                float4 v = *(const float4*)&inputs[(size_t)row * Dn + lane * 4];
                a0 += bfu2f(((unsigned)bf16r(v.x * cw)) << 16);
                a1 += bfu2f(((unsigned)bf16r(v.y * cw)) << 16);
                a2 += bfu2f(((unsigned)bf16r(v.z * cw)) << 16);
                a3 += bfu2f(((unsigned)bf16r(v.w * cw)) << 16);
            }
            float inv = 1.0f / (float)cntj[j];
            a0 *= inv; a1 *= inv; a2 *= inv; a3 *= inv;
            float ss = a0*a0 + a1*a1 + a2*a2 + a3*a3;
            #pragma unroll
            for (int off = 32; off > 0; off >>= 1) ss += __shfl_xor(ss, off);
            float sc = 1.0f / fmaxf(sqrtf(ss), 1e-12f);
            short4v o;
            o[0] = (short)bf16r(a0 * sc); o[1] = (short)bf16r(a1 * sc);
            o[2] = (short)bf16r(a2 * sc); o[3] = (short)bf16r(a3 * sc);
            int s = b * MAXU + cb + 16 * j;
            *(short4v*)&pbf[(size_t)s * Dn + lane * 4] = o;
        }
    }
}

// ==== k3: 32 rois x ALL proto cols per block (R3/R4-proven verbatim). ====
// Softmax denominator stays in registers across the pc loop; one atomic per
// block; reads f32 inputs directly with bit-identical bf16 round-trip.
__global__ __launch_bounds__(256, 2) void k3_loss(
    const float* __restrict__ inputs, const float* __restrict__ cls,
    const unsigned short* __restrict__ pbf,
    const int* __restrict__ lblc_arr, const int* __restrict__ nuniq,
    const int* __restrict__ nvalid_arr,
    float* __restrict__ nll, int* __restrict__ tick, float* __restrict__ out)
{
    __shared__ __align__(16) unsigned short xs[TRr * Dn];      // 16 KB
    __shared__ __align__(16) unsigned short psb[2][TCc * KCs]; // 2 x 16 KB dbuf
    __shared__ int lblc[TRr];
    __shared__ float es_l[4][TRr];
    __shared__ float ds_l[4][TRr];

    const int t = threadIdx.x;
    const int lane = t & 63, w = t >> 6;
    const int q = lane >> 4, r15 = lane & 15;
    const int rt = blockIdx.x;
    const int b  = blockIdx.y;
    const int roiBase = rt * TRr;
    const int U = nuniq[b];
    const int nch = (U <= 0) ? 1 : ((U + TCc - 1) >> 7);

    if (t < TRr) lblc[t] = lblc_arr[b * Rn + roiBase + t];

#define ISSUE_PS(PC, ST, BUF)                                                \
    do {                                                                     \
        _Pragma("unroll")                                                    \
        for (int i_ = 0; i_ < 4; ++i_) {                                     \
            int ci_ = i_ * 256 + w * 64 + lane;                              \
            int pr_ = ci_ >> 3, gp_ = ci_ & 7;                               \
            int g_ = gp_ ^ (pr_ & 7);                                        \
            async16(&psb[BUF][(i_ * 256 + w * 64) * 8],                      \
                    pbf + (size_t)(b * MAXU + (PC) * TCc + pr_) * Dn         \
                        + (ST) * KCs + g_ * 8);                              \
        }                                                                    \
    } while (0)

    ISSUE_PS(0, 0, 0);                                // overlaps with A-convert

    // A-tile: f32 -> bf16 (bit-identical) -> swizzled LDS (gpos = g ^ (row&7))
    {
        const int row = t >> 3, seg = t & 7;          // 8 threads per roi row
        const size_t gbase = (size_t)(b * Rn + roiBase + row) * Dn + seg * 32;
        const float cw = cls[b * Rn + roiBase + row];
        #pragma unroll
        for (int jj = 0; jj < 4; ++jj) {
            float4 v0 = *(const float4*)&inputs[gbase + jj * 8];
            float4 v1 = *(const float4*)&inputs[gbase + jj * 8 + 4];
            short8 o;
            o[0] = (short)bf16r(v0.x * cw); o[1] = (short)bf16r(v0.y * cw);
            o[2] = (short)bf16r(v0.z * cw); o[3] = (short)bf16r(v0.w * cw);
            o[4] = (short)bf16r(v1.x * cw); o[5] = (short)bf16r(v1.y * cw);
            o[6] = (short)bf16r(v1.z * cw); o[7] = (short)bf16r(v1.w * cw);
            int gpos = (seg * 4 + jj) ^ (row & 7);
            *(short8*)&xs[row * Dn + gpos * 8] = o;
        }
    }
    __syncthreads();                                  // xs + ps[0] resident

    // preload all A fragments into registers: 64 VGPRs
    short8 areg[2][8];
    #pragma unroll
    for (int mt = 0; mt < 2; ++mt)
        #pragma unroll
        for (int kcs = 0; kcs < 8; ++kcs) {
            int row = mt * 16 + r15;
            int gpos = (kcs * 4 + q) ^ (row & 7);
            areg[mt][kcs] = *(const short8*)&xs[row * Dn + gpos * 8];
        }

    int lcr[2][4];
    float esum[2][4], dsum[2][4];
    #pragma unroll
    for (int mt = 0; mt < 2; ++mt)
        #pragma unroll
        for (int reg = 0; reg < 4; ++reg) {
            lcr[mt][reg] = lblc[mt * 16 + q * 4 + reg];
            esum[mt][reg] = 0.f; dsum[mt][reg] = 0.f;
        }

    for (int pc = 0; pc < nch; ++pc) {
        floatx4 acc[2][2];
        #pragma unroll
        for (int mt = 0; mt < 2; ++mt) {
            acc[mt][0] = (floatx4)0.f; acc[mt][1] = (floatx4)0.f;
        }

        #pragma unroll
        for (int st = 0; st < NSTG; ++st) {
            const int cur = st & 1;                   // NSTG even -> static parity
            __syncthreads();                          // ps[cur] resident
            int ns = pc * NSTG + st + 1;
            if (ns < nch * NSTG) ISSUE_PS(ns >> 2, ns & 3, cur ^ 1);
            #pragma unroll
            for (int kk = 0; kk < 2; ++kk) {
                short8 bb[2];
                #pragma unroll
                for (int nt = 0; nt < 2; ++nt) {
                    int r = w * 32 + nt * 16 + r15;
                    int gpos = (kk * 4 + q) ^ (r & 7);
                    bb[nt] = *(const short8*)&psb[cur][r * KCs + gpos * 8];
                }
                #pragma unroll
                for (int mt = 0; mt < 2; ++mt) {
                    acc[mt][0] = __builtin_amdgcn_mfma_f32_16x16x32_bf16(
                        areg[mt][st * 2 + kk], bb[0], acc[mt][0], 0, 0, 0);
                    acc[mt][1] = __builtin_amdgcn_mfma_f32_16x16x32_bf16(
                        areg[mt][st * 2 + kk], bb[1], acc[mt][1], 0, 0, 0);
                }
            }
        }

        // per-pc epilogue in registers; C/D: n = r15, m = q*4 + reg
        #pragma unroll
        for (int nt = 0; nt < 2; ++nt) {
            int c = pc * TCc + w * 32 + nt * 16 + r15;
            bool v = c < U;
            #pragma unroll
            for (int mt = 0; mt < 2; ++mt)
                #pragma unroll
                for (int reg = 0; reg < 4; ++reg) {
                    float d = acc[mt][nt][reg];
                    if (v) esum[mt][reg] += __expf(d);
                    if (c == lcr[mt][reg]) dsum[mt][reg] += d;
                }
        }
    }
#undef ISSUE_PS

    // cross-lane (16) then cross-wave (LDS) combine; one atomic per block
    #pragma unroll
    for (int mt = 0; mt < 2; ++mt)
        #pragma unroll
        for (int reg = 0; reg < 4; ++reg) {
            float e = esum[mt][reg], d = dsum[mt][reg];
            #pragma unroll
            for (int off = 1; off < 16; off <<= 1) {
                e += __shfl_xor(e, off);
                d += __shfl_xor(d, off);
            }
            if (r15 == 0) {
                int row = mt * 16 + q * 4 + reg;
                es_l[w][row] = e;
                ds_l[w][row] = d;
            }
        }
    __syncthreads();
    if (t < TRr) {
        float es = es_l[0][t] + es_l[1][t] + es_l[2][t] + es_l[3][t];
        float ds = ds_l[0][t] + ds_l[1][t] + ds_l[2][t] + ds_l[3][t];
        float val = (lblc[t] >= 0) ? (__logf(es) - ds) : 0.f;
        #pragma unroll
        for (int off = 1; off < 32; off <<= 1) val += __shfl_xor(val, off);
        if (t == 0) {
            atomicAdd(nll, val);
            __threadfence();                          // order nll add vs ticket
            int old = atomicAdd(tick, 1);
            if (old == NBLK - 1) {                    // last block finalizes
                float total = atomicAdd(nll, 0.0f);   // coherent read
                int nv = 0;
                #pragma unroll
                for (int i = 0; i < Bn / 4; ++i) {
                    int4 vv = ((const int4*)nvalid_arr)[i];
                    nv += vv.x + vv.y + vv.z + vv.w;
                }
                out[0] = total / fmaxf((float)nv, 1.0f);
            }
        }
    }
}

extern "C" void kernel_launch(void* const* d_in, const int* in_sizes, int n_in,
                              void* d_out, int out_size, void* d_ws, size_t ws_size,
                              hipStream_t stream) {
    const float* inputs = (const float*)d_in[0];
    const float* cls    = (const float*)d_in[1];
    const int*   roi    = (const int*)d_in[2];
    int* wsi   = (int*)d_ws;
    float* out = (float*)d_out;

    unsigned short* pbf = (unsigned short*)(wsi + PBF_OFF);
    int*   lblc   = wsi + LBLC_OFF;
    int*   nuniq  = wsi + NUNIQ_OFF;
    int*   nvalid = wsi + NVALID_OFF;
    float* nll    = (float*)(wsi + NLL_OFF);
    int*   tick   = wsi + TICK_OFF;

    k12_prep_proto<<<Bn, 1024, 0, stream>>>(inputs, cls, roi, pbf, lblc,
                                            nuniq, nvalid, wsi + NLL_OFF);
    dim3 g(Rn / TRr, Bn);
    k3_loss<<<g, 256, 0, stream>>>(inputs, cls, pbf, lblc, nuniq, nvalid,
                                   nll, tick, out);
}

// Round 6
// 107.405 us; speedup vs baseline: 1.7814x; 1.1807x over previous
//
#include <hip/hip_runtime.h>
#include <math.h>

#define Bn 32
#define Rn 512
#define Dn 256
#define Pn 5532
#define MAXU 512

#define TRr 32
#define TCc 128
#define KCs 64
#define NSTG (Dn / KCs)                               // 4 stages per pc chunk
#define NBLK ((Rn / TRr) * Bn)                        // 512 blocks in k3

// ---- workspace layout (4-byte words). nll+tick zeroed by k1 block 0 each
// call; everything else read-after-write in-call (poison-safe: pbf rows >= U
// are loaded but value-gated, proven benign R0-R5).
#define PBF_OFF    0
#define PBF_WORDS  (Bn*MAXU*Dn/2)
#define LBLC_OFF   (PBF_OFF + PBF_WORDS)
#define CCNT_OFF   (LBLC_OFF + Bn*Rn)
#define CURS_OFF   (CCNT_OFF + Bn*MAXU)               // END offsets (R0 scheme)
#define RLIST_OFF  (CURS_OFF + Bn*MAXU)
#define NUNIQ_OFF  (RLIST_OFF + Bn*Rn)
#define NVALID_OFF (NUNIQ_OFF + 32)
#define NLL_OFF    (NVALID_OFF + 32)
#define TICK_OFF   (NLL_OFF + 1)

typedef short short8 __attribute__((ext_vector_type(8)));
typedef short short4v __attribute__((ext_vector_type(4)));
typedef float floatx4 __attribute__((ext_vector_type(4)));

__device__ __forceinline__ unsigned short bf16r(float f) {   // fp32 -> bf16 RNE
    union { float f; unsigned int u; } c; c.f = f;
    return (unsigned short)((c.u + 0x7FFFu + ((c.u >> 16) & 1u)) >> 16);
}
__device__ __forceinline__ float bfu2f(unsigned int hi16) {  // <<16'd bf16 -> f32
    union { unsigned int u; float f; } c; c.u = hi16;
    return c.f;
}

// async global->LDS, 16B per lane. LDS dest = wave-uniform base + lane*16.
__device__ __forceinline__ void async16(void* lds, const void* g) {
    auto* l3 = reinterpret_cast<__attribute__((address_space(3))) unsigned int*>(
                   reinterpret_cast<size_t>(lds));
    auto* g1 = reinterpret_cast<const __attribute__((address_space(1))) unsigned int*>(
                   reinterpret_cast<size_t>(g));
    __builtin_amdgcn_global_load_lds(g1, l3, 16, 0, 0);
}

// ==== k1: per-image in-LDS compact (R0-proven verbatim, convert pass deleted;
// R5 showed the 32-block gather is ~60us latency-bound, so gather stays in a
// separate high-occupancy dispatch). ====
__global__ __launch_bounds__(1024) void k1_compact(
    const int* __restrict__ roi_label,
    int* __restrict__ lblc_arr, int* __restrict__ ccnt, int* __restrict__ cursor,
    int* __restrict__ rlist, int* __restrict__ nuniq, int* __restrict__ nvalid_arr,
    int* __restrict__ zwords)
{
    __shared__ int cnt_lds[Pn];                       // 22.1 KB
    __shared__ int cmap_lds[Pn];                      // 22.1 KB
    __shared__ int curs_lds[MAXU];
    __shared__ int wpres[16], wcnt[16];

    const int b = blockIdx.x;
    const int t = threadIdx.x;
    const int lane = t & 63, wid = t >> 6;            // 16 waves

    if (b == 0 && t == 0) { zwords[0] = 0; zwords[1] = 0; }   // nll, tick

    for (int i = t; i < Pn; i += 1024) cnt_lds[i] = 0;
    __syncthreads();
    int mylbl = -1;
    if (t < Rn) {
        mylbl = roi_label[b * Rn + t] - 1;
        if (mylbl >= 0) atomicAdd(&cnt_lds[mylbl], 1);
    }
    __syncthreads();

    int basePres = 0, baseCnt = 0;                    // replicated in all threads
    for (int i0 = 0; i0 < Pn; i0 += 1024) {           // 6 chunks
        int i = i0 + t;
        int cnt = (i < Pn) ? cnt_lds[i] : 0;
        bool pres = cnt > 0;
        unsigned long long mask = __ballot(pres);
        int pfx_pres = __popcll(mask & ((1ULL << lane) - 1ULL));
        int v = cnt;
        #pragma unroll
        for (int off = 1; off < 64; off <<= 1) {
            int u = __shfl_up(v, off);
            if (lane >= off) v += u;
        }
        int pfx_cnt = v - cnt;                        // exclusive
        if (lane == 63) { wpres[wid] = __popcll(mask); wcnt[wid] = v; }
        __syncthreads();
        int woffP = 0, totP = 0, woffC = 0, totC = 0;
        #pragma unroll
        for (int w = 0; w < 16; ++w) {
            int p = wpres[w], c = wcnt[w];
            if (w < wid) { woffP += p; woffC += c; }
            totP += p; totC += c;
        }
        if (pres) {
            int c = basePres + woffP + pfx_pres;      // compact slot < MAXU
            cmap_lds[i] = c;
            ccnt[b * MAXU + c] = cnt;
            curs_lds[c] = baseCnt + woffC + pfx_cnt;  // start offset
        }
        basePres += totP; baseCnt += totC;
        __syncthreads();
    }
    // per-roi compact label + scatter to global rlist via LDS cursors
    if (t < Rn) {
        int lc = (mylbl >= 0) ? cmap_lds[mylbl] : -1;
        lblc_arr[b * Rn + t] = lc;
        if (lc >= 0) {
            int pos = atomicAdd(&curs_lds[lc], 1);
            rlist[b * Rn + pos] = t;
        }
    }
    __syncthreads();
    if (t < MAXU && t < basePres)
        cursor[b * MAXU + t] = curs_lds[t];           // END offset (= start + cnt)
    if (t == 0) { nuniq[b] = basePres; nvalid_arr[b] = baseCnt; }
}

// ==== k2: gather f32 inputs (bf16 round-trip, bit-identical) -> mean ->
// L2 normalize -> bf16 proto. One slot per WAVE, 4096 blocks (R0-proven
// occupancy; full-chip TLP hides the gather chain latency). ====
__global__ __launch_bounds__(256) void k2_proto(
    const float* __restrict__ inputs, const float* __restrict__ cls,
    const int* __restrict__ nuniq, const int* __restrict__ ccnt,
    const int* __restrict__ cursor, const int* __restrict__ rlist,
    unsigned short* __restrict__ pbf)
{
    const int lane = threadIdx.x & 63, wv = threadIdx.x >> 6;
    int s = blockIdx.x * 4 + wv;                      // 4096 blocks -> 16384 slots
    int b = s >> 9;
    int c = s & (MAXU - 1);
    if (c >= nuniq[b]) return;                        // wave-uniform exit
    int cnt = ccnt[s];
    int start = cursor[s] - cnt;
    float a0 = 0.f, a1 = 0.f, a2 = 0.f, a3 = 0.f;
    for (int k = 0; k < cnt; ++k) {
        int row = b * Rn + rlist[b * Rn + start + k];
        float cw = cls[row];
        float4 v = *(const float4*)&inputs[(size_t)row * Dn + lane * 4];
        // bf16 round-trip: bit-identical to the proven xbf path
        a0 += bfu2f(((unsigned)bf16r(v.x * cw)) << 16);
        a1 += bfu2f(((unsigned)bf16r(v.y * cw)) << 16);
        a2 += bfu2f(((unsigned)bf16r(v.z * cw)) << 16);
        a3 += bfu2f(((unsigned)bf16r(v.w * cw)) << 16);
    }
    float inv = 1.0f / (float)cnt;
    a0 *= inv; a1 *= inv; a2 *= inv; a3 *= inv;
    float ss = a0*a0 + a1*a1 + a2*a2 + a3*a3;
    #pragma unroll
    for (int off = 32; off > 0; off >>= 1) ss += __shfl_xor(ss, off);
    float sc = 1.0f / fmaxf(sqrtf(ss), 1e-12f);
    short4v o;
    o[0] = (short)bf16r(a0 * sc); o[1] = (short)bf16r(a1 * sc);
    o[2] = (short)bf16r(a2 * sc); o[3] = (short)bf16r(a3 * sc);
    *(short4v*)&pbf[(size_t)s * Dn + lane * 4] = o;
}

// ==== k3: 32 rois x ALL proto cols per block (R4/R5-proven verbatim). ====
// Softmax denominator stays in registers across the pc loop; one atomic per
// block; reads f32 inputs directly with bit-identical bf16 round-trip.
__global__ __launch_bounds__(256, 2) void k3_loss(
    const float* __restrict__ inputs, const float* __restrict__ cls,
    const unsigned short* __restrict__ pbf,
    const int* __restrict__ lblc_arr, const int* __restrict__ nuniq,
    const int* __restrict__ nvalid_arr,
    float* __restrict__ nll, int* __restrict__ tick, float* __restrict__ out)
{
    __shared__ __align__(16) unsigned short xs[TRr * Dn];      // 16 KB
    __shared__ __align__(16) unsigned short psb[2][TCc * KCs]; // 2 x 16 KB dbuf
    __shared__ int lblc[TRr];
    __shared__ float es_l[4][TRr];
    __shared__ float ds_l[4][TRr];

    const int t = threadIdx.x;
    const int lane = t & 63, w = t >> 6;
    const int q = lane >> 4, r15 = lane & 15;
    const int rt = blockIdx.x;
    const int b  = blockIdx.y;
    const int roiBase = rt * TRr;
    const int U = nuniq[b];
    const int nch = (U <= 0) ? 1 : ((U + TCc - 1) >> 7);

    if (t < TRr) lblc[t] = lblc_arr[b * Rn + roiBase + t];

#define ISSUE_PS(PC, ST, BUF)                                                \
    do {                                                                     \
        _Pragma("unroll")                                                    \
        for (int i_ = 0; i_ < 4; ++i_) {                                     \
            int ci_ = i_ * 256 + w * 64 + lane;                              \
            int pr_ = ci_ >> 3, gp_ = ci_ & 7;                               \
            int g_ = gp_ ^ (pr_ & 7);                                        \
            async16(&psb[BUF][(i_ * 256 + w * 64) * 8],                      \
                    pbf + (size_t)(b * MAXU + (PC) * TCc + pr_) * Dn         \
                        + (ST) * KCs + g_ * 8);                              \
        }                                                                    \
    } while (0)

    ISSUE_PS(0, 0, 0);                                // overlaps with A-convert

    // A-tile: f32 -> bf16 (bit-identical) -> swizzled LDS (gpos = g ^ (row&7))
    {
        const int row = t >> 3, seg = t & 7;          // 8 threads per roi row
        const size_t gbase = (size_t)(b * Rn + roiBase + row) * Dn + seg * 32;
        const float cw = cls[b * Rn + roiBase + row];
        #pragma unroll
        for (int jj = 0; jj < 4; ++jj) {
            float4 v0 = *(const float4*)&inputs[gbase + jj * 8];
            float4 v1 = *(const float4*)&inputs[gbase + jj * 8 + 4];
            short8 o;
            o[0] = (short)bf16r(v0.x * cw); o[1] = (short)bf16r(v0.y * cw);
            o[2] = (short)bf16r(v0.z * cw); o[3] = (short)bf16r(v0.w * cw);
            o[4] = (short)bf16r(v1.x * cw); o[5] = (short)bf16r(v1.y * cw);
            o[6] = (short)bf16r(v1.z * cw); o[7] = (short)bf16r(v1.w * cw);
            int gpos = (seg * 4 + jj) ^ (row & 7);
            *(short8*)&xs[row * Dn + gpos * 8] = o;
        }
    }
    __syncthreads();                                  // xs + ps[0] resident

    // preload all A fragments into registers: 64 VGPRs
    short8 areg[2][8];
    #pragma unroll
    for (int mt = 0; mt < 2; ++mt)
        #pragma unroll
        for (int kcs = 0; kcs < 8; ++kcs) {
            int row = mt * 16 + r15;
            int gpos = (kcs * 4 + q) ^ (row & 7);
            areg[mt][kcs] = *(const short8*)&xs[row * Dn + gpos * 8];
        }

    int lcr[2][4];
    float esum[2][4], dsum[2][4];
    #pragma unroll
    for (int mt = 0; mt < 2; ++mt)
        #pragma unroll
        for (int reg = 0; reg < 4; ++reg) {
            lcr[mt][reg] = lblc[mt * 16 + q * 4 + reg];
            esum[mt][reg] = 0.f; dsum[mt][reg] = 0.f;
        }

    for (int pc = 0; pc < nch; ++pc) {
        floatx4 acc[2][2];
        #pragma unroll
        for (int mt = 0; mt < 2; ++mt) {
            acc[mt][0] = (floatx4)0.f; acc[mt][1] = (floatx4)0.f;
        }

        #pragma unroll
        for (int st = 0; st < NSTG; ++st) {
            const int cur = st & 1;                   // NSTG even -> static parity
            __syncthreads();                          // ps[cur] resident
            int ns = pc * NSTG + st + 1;
            if (ns < nch * NSTG) ISSUE_PS(ns >> 2, ns & 3, cur ^ 1);
            #pragma unroll
            for (int kk = 0; kk < 2; ++kk) {
                short8 bb[2];
                #pragma unroll
                for (int nt = 0; nt < 2; ++nt) {
                    int r = w * 32 + nt * 16 + r15;
                    int gpos = (kk * 4 + q) ^ (r & 7);
                    bb[nt] = *(const short8*)&psb[cur][r * KCs + gpos * 8];
                }
                #pragma unroll
                for (int mt = 0; mt < 2; ++mt) {
                    acc[mt][0] = __builtin_amdgcn_mfma_f32_16x16x32_bf16(
                        areg[mt][st * 2 + kk], bb[0], acc[mt][0], 0, 0, 0);
                    acc[mt][1] = __builtin_amdgcn_mfma_f32_16x16x32_bf16(
                        areg[mt][st * 2 + kk], bb[1], acc[mt][1], 0, 0, 0);
                }
            }
        }

        // per-pc epilogue in registers; C/D: n = r15, m = q*4 + reg
        #pragma unroll
        for (int nt = 0; nt < 2; ++nt) {
            int c = pc * TCc + w * 32 + nt * 16 + r15;
            bool v = c < U;
            #pragma unroll
            for (int mt = 0; mt < 2; ++mt)
                #pragma unroll
                for (int reg = 0; reg < 4; ++reg) {
                    float d = acc[mt][nt][reg];
                    if (v) esum[mt][reg] += __expf(d);
                    if (c == lcr[mt][reg]) dsum[mt][reg] += d;
                }
        }
    }
#undef ISSUE_PS

    // cross-lane (16) then cross-wave (LDS) combine; one atomic per block
    #pragma unroll
    for (int mt = 0; mt < 2; ++mt)
        #pragma unroll
        for (int reg = 0; reg < 4; ++reg) {
            float e = esum[mt][reg], d = dsum[mt][reg];
            #pragma unroll
            for (int off = 1; off < 16; off <<= 1) {
                e += __shfl_xor(e, off);
                d += __shfl_xor(d, off);
            }
            if (r15 == 0) {
                int row = mt * 16 + q * 4 + reg;
                es_l[w][row] = e;
                ds_l[w][row] = d;
            }
        }
    __syncthreads();
    if (t < TRr) {
        float es = es_l[0][t] + es_l[1][t] + es_l[2][t] + es_l[3][t];
        float ds = ds_l[0][t] + ds_l[1][t] + ds_l[2][t] + ds_l[3][t];
        float val = (lblc[t] >= 0) ? (__logf(es) - ds) : 0.f;
        #pragma unroll
        for (int off = 1; off < 32; off <<= 1) val += __shfl_xor(val, off);
        if (t == 0) {
            atomicAdd(nll, val);
            __threadfence();                          // order nll add vs ticket
            int old = atomicAdd(tick, 1);
            if (old == NBLK - 1) {                    // last block finalizes
                float total = atomicAdd(nll, 0.0f);   // coherent read
                int nv = 0;
                #pragma unroll
                for (int i = 0; i < Bn / 4; ++i) {
                    int4 vv = ((const int4*)nvalid_arr)[i];
                    nv += vv.x + vv.y + vv.z + vv.w;
                }
                out[0] = total / fmaxf((float)nv, 1.0f);
            }
        }
    }
}

extern "C" void kernel_launch(void* const* d_in, const int* in_sizes, int n_in,
                              void* d_out, int out_size, void* d_ws, size_t ws_size,
                              hipStream_t stream) {
    const float* inputs = (const float*)d_in[0];
    const float* cls    = (const float*)d_in[1];
    const int*   roi    = (const int*)d_in[2];
    int* wsi   = (int*)d_ws;
    float* out = (float*)d_out;

    unsigned short* pbf = (unsigned short*)(wsi + PBF_OFF);
    int*   lblc   = wsi + LBLC_OFF;
    int*   ccnt   = wsi + CCNT_OFF;
    int*   cursor = wsi + CURS_OFF;
    int*   rlist  = wsi + RLIST_OFF;
    int*   nuniq  = wsi + NUNIQ_OFF;
    int*   nvalid = wsi + NVALID_OFF;
    float* nll    = (float*)(wsi + NLL_OFF);
    int*   tick   = wsi + TICK_OFF;

    k1_compact<<<Bn, 1024, 0, stream>>>(roi, lblc, ccnt, cursor, rlist,
                                        nuniq, nvalid, wsi + NLL_OFF);
    k2_proto<<<(Bn * MAXU) / 4, 256, 0, stream>>>(inputs, cls, nuniq, ccnt,
                                                  cursor, rlist, pbf);
    dim3 g(Rn / TRr, Bn);
    k3_loss<<<g, 256, 0, stream>>>(inputs, cls, pbf, lblc, nuniq, nvalid,
                                   nll, tick, out);
}

// Round 7
// 104.709 us; speedup vs baseline: 1.8273x; 1.0257x over previous
//
#include <hip/hip_runtime.h>
#include <math.h>

#define Bn 32
#define Rn 512
#define Dn 256
#define Pn 5532
#define MAXU 512

#define TRr 32
#define TCc 128
#define KCs 64
#define NSTG (Dn / KCs)                               // 4 stages per pc chunk
#define NBLK ((Rn / TRr) * Bn)                        // 512 blocks in k3

// ---- workspace layout (4-byte words). nll+tick zeroed by k1 block 0 each
// call; everything else read-after-write in-call (poison-safe: pbf rows >= U
// are loaded but value-gated, proven benign R0-R6).
#define PBF_OFF    0
#define PBF_WORDS  (Bn*MAXU*Dn/2)
#define LBLC_OFF   (PBF_OFF + PBF_WORDS)
#define CCNT_OFF   (LBLC_OFF + Bn*Rn)
#define CURS_OFF   (CCNT_OFF + Bn*MAXU)               // END offsets (R0 scheme)
#define RLIST_OFF  (CURS_OFF + Bn*MAXU)
#define NUNIQ_OFF  (RLIST_OFF + Bn*Rn)
#define NVALID_OFF (NUNIQ_OFF + 32)
#define NLL_OFF    (NVALID_OFF + 32)
#define TICK_OFF   (NLL_OFF + 1)

typedef short short8 __attribute__((ext_vector_type(8)));
typedef short short4v __attribute__((ext_vector_type(4)));
typedef float floatx4 __attribute__((ext_vector_type(4)));

__device__ __forceinline__ unsigned short bf16r(float f) {   // fp32 -> bf16 RNE
    union { float f; unsigned int u; } c; c.f = f;
    return (unsigned short)((c.u + 0x7FFFu + ((c.u >> 16) & 1u)) >> 16);
}
__device__ __forceinline__ float bfu2f(unsigned int hi16) {  // <<16'd bf16 -> f32
    union { unsigned int u; float f; } c; c.u = hi16;
    return c.f;
}

// async global->LDS, 16B per lane. LDS dest = wave-uniform base + lane*16.
__device__ __forceinline__ void async16(void* lds, const void* g) {
    auto* l3 = reinterpret_cast<__attribute__((address_space(3))) unsigned int*>(
                   reinterpret_cast<size_t>(lds));
    auto* g1 = reinterpret_cast<const __attribute__((address_space(1))) unsigned int*>(
                   reinterpret_cast<size_t>(g));
    __builtin_amdgcn_global_load_lds(g1, l3, 16, 0, 0);
}

// ==== k1: per-image in-LDS compact (R0/R6-proven verbatim). blockIdx.x = b
// -> XCD = b%8 naturally: per-image metadata lands in the L2 that k2/k3's
// XCD-pinned blocks will read. ====
__global__ __launch_bounds__(1024) void k1_compact(
    const int* __restrict__ roi_label,
    int* __restrict__ lblc_arr, int* __restrict__ ccnt, int* __restrict__ cursor,
    int* __restrict__ rlist, int* __restrict__ nuniq, int* __restrict__ nvalid_arr,
    int* __restrict__ zwords)
{
    __shared__ int cnt_lds[Pn];                       // 22.1 KB
    __shared__ int cmap_lds[Pn];                      // 22.1 KB
    __shared__ int curs_lds[MAXU];
    __shared__ int wpres[16], wcnt[16];

    const int b = blockIdx.x;
    const int t = threadIdx.x;
    const int lane = t & 63, wid = t >> 6;            // 16 waves

    if (b == 0 && t == 0) { zwords[0] = 0; zwords[1] = 0; }   // nll, tick

    for (int i = t; i < Pn; i += 1024) cnt_lds[i] = 0;
    __syncthreads();
    int mylbl = -1;
    if (t < Rn) {
        mylbl = roi_label[b * Rn + t] - 1;
        if (mylbl >= 0) atomicAdd(&cnt_lds[mylbl], 1);
    }
    __syncthreads();

    int basePres = 0, baseCnt = 0;                    // replicated in all threads
    for (int i0 = 0; i0 < Pn; i0 += 1024) {           // 6 chunks
        int i = i0 + t;
        int cnt = (i < Pn) ? cnt_lds[i] : 0;
        bool pres = cnt > 0;
        unsigned long long mask = __ballot(pres);
        int pfx_pres = __popcll(mask & ((1ULL << lane) - 1ULL));
        int v = cnt;
        #pragma unroll
        for (int off = 1; off < 64; off <<= 1) {
            int u = __shfl_up(v, off);
            if (lane >= off) v += u;
        }
        int pfx_cnt = v - cnt;                        // exclusive
        if (lane == 63) { wpres[wid] = __popcll(mask); wcnt[wid] = v; }
        __syncthreads();
        int woffP = 0, totP = 0, woffC = 0, totC = 0;
        #pragma unroll
        for (int w = 0; w < 16; ++w) {
            int p = wpres[w], c = wcnt[w];
            if (w < wid) { woffP += p; woffC += c; }
            totP += p; totC += c;
        }
        if (pres) {
            int c = basePres + woffP + pfx_pres;      // compact slot < MAXU
            cmap_lds[i] = c;
            ccnt[b * MAXU + c] = cnt;
            curs_lds[c] = baseCnt + woffC + pfx_cnt;  // start offset
        }
        basePres += totP; baseCnt += totC;
        __syncthreads();
    }
    // per-roi compact label + scatter to global rlist via LDS cursors
    if (t < Rn) {
        int lc = (mylbl >= 0) ? cmap_lds[mylbl] : -1;
        lblc_arr[b * Rn + t] = lc;
        if (lc >= 0) {
            int pos = atomicAdd(&curs_lds[lc], 1);
            rlist[b * Rn + pos] = t;
        }
    }
    __syncthreads();
    if (t < MAXU && t < basePres)
        cursor[b * MAXU + t] = curs_lds[t];           // END offset (= start + cnt)
    if (t == 0) { nuniq[b] = basePres; nvalid_arr[b] = baseCnt; }
}

// ==== k2: gather f32 inputs (bf16 round-trip, bit-identical) -> mean ->
// L2 normalize -> bf16 proto. One slot per WAVE, 4096 blocks. XCD-pinned:
// block h (XCD h%8) handles images b with b%8 == h%8, so pbf[b] is written
// from — and stays resident in — the L2 that k3 reads it from. ====
__global__ __launch_bounds__(256) void k2_proto(
    const float* __restrict__ inputs, const float* __restrict__ cls,
    const int* __restrict__ nuniq, const int* __restrict__ ccnt,
    const int* __restrict__ cursor, const int* __restrict__ rlist,
    unsigned short* __restrict__ pbf)
{
    const int lane = threadIdx.x & 63, wv = threadIdx.x >> 6;
    const int h = blockIdx.x;                         // [0,4096)
    const int xcd = h & 7, widx = h >> 3;             // widx in [0,512)
    const int b = xcd + 8 * (widx >> 7);              // image pinned to XCD b%8
    const int inner = widx & 127;                     // [0,128) blocks per image
    int c = inner * 4 + wv;                           // slot within image
    int s = b * MAXU + c;
    if (c >= nuniq[b]) return;                        // wave-uniform exit
    int cnt = ccnt[s];
    int start = cursor[s] - cnt;
    float a0 = 0.f, a1 = 0.f, a2 = 0.f, a3 = 0.f;
    for (int k = 0; k < cnt; ++k) {
        int row = b * Rn + rlist[b * Rn + start + k];
        float cw = cls[row];
        float4 v = *(const float4*)&inputs[(size_t)row * Dn + lane * 4];
        // bf16 round-trip: bit-identical to the proven xbf path
        a0 += bfu2f(((unsigned)bf16r(v.x * cw)) << 16);
        a1 += bfu2f(((unsigned)bf16r(v.y * cw)) << 16);
        a2 += bfu2f(((unsigned)bf16r(v.z * cw)) << 16);
        a3 += bfu2f(((unsigned)bf16r(v.w * cw)) << 16);
    }
    float inv = 1.0f / (float)cnt;
    a0 *= inv; a1 *= inv; a2 *= inv; a3 *= inv;
    float ss = a0*a0 + a1*a1 + a2*a2 + a3*a3;
    #pragma unroll
    for (int off = 32; off > 0; off >>= 1) ss += __shfl_xor(ss, off);
    float sc = 1.0f / fmaxf(sqrtf(ss), 1e-12f);
    short4v o;
    o[0] = (short)bf16r(a0 * sc); o[1] = (short)bf16r(a1 * sc);
    o[2] = (short)bf16r(a2 * sc); o[3] = (short)bf16r(a3 * sc);
    *(short4v*)&pbf[(size_t)s * Dn + lane * 4] = o;
}

// ==== k3: 32 rois x ALL proto cols per block (R4-R6-proven body). 1-D grid
// with XCD-pinned decode: the 16 blocks sharing image b's 256KB pbf panel all
// run on XCD b%8 (was dim3(16,32): panel re-fetched by all 8 XCDs, ~48MB HBM
// for 8MB of protos). ====
__global__ __launch_bounds__(256, 2) void k3_loss(
    const float* __restrict__ inputs, const float* __restrict__ cls,
    const unsigned short* __restrict__ pbf,
    const int* __restrict__ lblc_arr, const int* __restrict__ nuniq,
    const int* __restrict__ nvalid_arr,
    float* __restrict__ nll, int* __restrict__ tick, float* __restrict__ out)
{
    __shared__ __align__(16) unsigned short xs[TRr * Dn];      // 16 KB
    __shared__ __align__(16) unsigned short psb[2][TCc * KCs]; // 2 x 16 KB dbuf
    __shared__ int lblc[TRr];
    __shared__ float es_l[4][TRr];
    __shared__ float ds_l[4][TRr];

    const int t = threadIdx.x;
    const int lane = t & 63, w = t >> 6;
    const int q = lane >> 4, r15 = lane & 15;
    const int h = blockIdx.x;                         // [0,512)
    const int xcd = h & 7, widx = h >> 3;             // widx in [0,64)
    const int b  = xcd + 8 * (widx >> 4);             // image pinned to XCD b%8
    const int rt = widx & 15;
    const int roiBase = rt * TRr;
    const int U = nuniq[b];
    const int nch = (U <= 0) ? 1 : ((U + TCc - 1) >> 7);

    if (t < TRr) lblc[t] = lblc_arr[b * Rn + roiBase + t];

#define ISSUE_PS(PC, ST, BUF)                                                \
    do {                                                                     \
        _Pragma("unroll")                                                    \
        for (int i_ = 0; i_ < 4; ++i_) {                                     \
            int ci_ = i_ * 256 + w * 64 + lane;                              \
            int pr_ = ci_ >> 3, gp_ = ci_ & 7;                               \
            int g_ = gp_ ^ (pr_ & 7);                                        \
            async16(&psb[BUF][(i_ * 256 + w * 64) * 8],                      \
                    pbf + (size_t)(b * MAXU + (PC) * TCc + pr_) * Dn         \
                        + (ST) * KCs + g_ * 8);                              \
        }                                                                    \
    } while (0)

    ISSUE_PS(0, 0, 0);                                // overlaps with A-convert

    // A-tile: f32 -> bf16 (bit-identical) -> swizzled LDS (gpos = g ^ (row&7))
    {
        const int row = t >> 3, seg = t & 7;          // 8 threads per roi row
        const size_t gbase = (size_t)(b * Rn + roiBase + row) * Dn + seg * 32;
        const float cw = cls[b * Rn + roiBase + row];
        #pragma unroll
        for (int jj = 0; jj < 4; ++jj) {
            float4 v0 = *(const float4*)&inputs[gbase + jj * 8];
            float4 v1 = *(const float4*)&inputs[gbase + jj * 8 + 4];
            short8 o;
            o[0] = (short)bf16r(v0.x * cw); o[1] = (short)bf16r(v0.y * cw);
            o[2] = (short)bf16r(v0.z * cw); o[3] = (short)bf16r(v0.w * cw);
            o[4] = (short)bf16r(v1.x * cw); o[5] = (short)bf16r(v1.y * cw);
            o[6] = (short)bf16r(v1.z * cw); o[7] = (short)bf16r(v1.w * cw);
            int gpos = (seg * 4 + jj) ^ (row & 7);
            *(short8*)&xs[row * Dn + gpos * 8] = o;
        }
    }
    __syncthreads();                                  // xs + ps[0] resident

    // preload all A fragments into registers: 64 VGPRs
    short8 areg[2][8];
    #pragma unroll
    for (int mt = 0; mt < 2; ++mt)
        #pragma unroll
        for (int kcs = 0; kcs < 8; ++kcs) {
            int row = mt * 16 + r15;
            int gpos = (kcs * 4 + q) ^ (row & 7);
            areg[mt][kcs] = *(const short8*)&xs[row * Dn + gpos * 8];
        }

    int lcr[2][4];
    float esum[2][4], dsum[2][4];
    #pragma unroll
    for (int mt = 0; mt < 2; ++mt)
        #pragma unroll
        for (int reg = 0; reg < 4; ++reg) {
            lcr[mt][reg] = lblc[mt * 16 + q * 4 + reg];
            esum[mt][reg] = 0.f; dsum[mt][reg] = 0.f;
        }

    for (int pc = 0; pc < nch; ++pc) {
        floatx4 acc[2][2];
        #pragma unroll
        for (int mt = 0; mt < 2; ++mt) {
            acc[mt][0] = (floatx4)0.f; acc[mt][1] = (floatx4)0.f;
        }

        #pragma unroll
        for (int st = 0; st < NSTG; ++st) {
            const int cur = st & 1;                   // NSTG even -> static parity
            __syncthreads();                          // ps[cur] resident
            int ns = pc * NSTG + st + 1;
            if (ns < nch * NSTG) ISSUE_PS(ns >> 2, ns & 3, cur ^ 1);
            #pragma unroll
            for (int kk = 0; kk < 2; ++kk) {
                short8 bb[2];
                #pragma unroll
                for (int nt = 0; nt < 2; ++nt) {
                    int r = w * 32 + nt * 16 + r15;
                    int gpos = (kk * 4 + q) ^ (r & 7);
                    bb[nt] = *(const short8*)&psb[cur][r * KCs + gpos * 8];
                }
                #pragma unroll
                for (int mt = 0; mt < 2; ++mt) {
                    acc[mt][0] = __builtin_amdgcn_mfma_f32_16x16x32_bf16(
                        areg[mt][st * 2 + kk], bb[0], acc[mt][0], 0, 0, 0);
                    acc[mt][1] = __builtin_amdgcn_mfma_f32_16x16x32_bf16(
                        areg[mt][st * 2 + kk], bb[1], acc[mt][1], 0, 0, 0);
                }
            }
        }

        // per-pc epilogue in registers; C/D: n = r15, m = q*4 + reg
        #pragma unroll
        for (int nt = 0; nt < 2; ++nt) {
            int c = pc * TCc + w * 32 + nt * 16 + r15;
            bool v = c < U;
            #pragma unroll
            for (int mt = 0; mt < 2; ++mt)
                #pragma unroll
                for (int reg = 0; reg < 4; ++reg) {
                    float d = acc[mt][nt][reg];
                    if (v) esum[mt][reg] += __expf(d);
                    if (c == lcr[mt][reg]) dsum[mt][reg] += d;
                }
        }
    }
#undef ISSUE_PS

    // cross-lane (16) then cross-wave (LDS) combine; one atomic per block
    #pragma unroll
    for (int mt = 0; mt < 2; ++mt)
        #pragma unroll
        for (int reg = 0; reg < 4; ++reg) {
            float e = esum[mt][reg], d = dsum[mt][reg];
            #pragma unroll
            for (int off = 1; off < 16; off <<= 1) {
                e += __shfl_xor(e, off);
                d += __shfl_xor(d, off);
            }
            if (r15 == 0) {
                int row = mt * 16 + q * 4 + reg;
                es_l[w][row] = e;
                ds_l[w][row] = d;
            }
        }
    __syncthreads();
    if (t < TRr) {
        float es = es_l[0][t] + es_l[1][t] + es_l[2][t] + es_l[3][t];
        float ds = ds_l[0][t] + ds_l[1][t] + ds_l[2][t] + ds_l[3][t];
        float val = (lblc[t] >= 0) ? (__logf(es) - ds) : 0.f;
        #pragma unroll
        for (int off = 1; off < 32; off <<= 1) val += __shfl_xor(val, off);
        if (t == 0) {
            atomicAdd(nll, val);
            __threadfence();                          // order nll add vs ticket
            int old = atomicAdd(tick, 1);
            if (old == NBLK - 1) {                    // last block finalizes
                float total = atomicAdd(nll, 0.0f);   // coherent read
                int nv = 0;
                #pragma unroll
                for (int i = 0; i < Bn / 4; ++i) {
                    int4 vv = ((const int4*)nvalid_arr)[i];
                    nv += vv.x + vv.y + vv.z + vv.w;
                }
                out[0] = total / fmaxf((float)nv, 1.0f);
            }
        }
    }
}

extern "C" void kernel_launch(void* const* d_in, const int* in_sizes, int n_in,
                              void* d_out, int out_size, void* d_ws, size_t ws_size,
                              hipStream_t stream) {
    const float* inputs = (const float*)d_in[0];
    const float* cls    = (const float*)d_in[1];
    const int*   roi    = (const int*)d_in[2];
    int* wsi   = (int*)d_ws;
    float* out = (float*)d_out;

    unsigned short* pbf = (unsigned short*)(wsi + PBF_OFF);
    int*   lblc   = wsi + LBLC_OFF;
    int*   ccnt   = wsi + CCNT_OFF;
    int*   cursor = wsi + CURS_OFF;
    int*   rlist  = wsi + RLIST_OFF;
    int*   nuniq  = wsi + NUNIQ_OFF;
    int*   nvalid = wsi + NVALID_OFF;
    float* nll    = (float*)(wsi + NLL_OFF);
    int*   tick   = wsi + TICK_OFF;

    k1_compact<<<Bn, 1024, 0, stream>>>(roi, lblc, ccnt, cursor, rlist,
                                        nuniq, nvalid, wsi + NLL_OFF);
    k2_proto<<<(Bn * MAXU) / 4, 256, 0, stream>>>(inputs, cls, nuniq, ccnt,
                                                  cursor, rlist, pbf);
    k3_loss<<<NBLK, 256, 0, stream>>>(inputs, cls, pbf, lblc, nuniq, nvalid,
                                      nll, tick, out);
}